// Round 8
// baseline (678.742 us; speedup 1.0000x reference)
//
#include <hip/hip_runtime.h>
#include <hip/hip_bf16.h>
#include <stdint.h>

#define H 128
#define SCAN_B 1024

typedef __attribute__((ext_vector_type(8))) short bf16x8;
typedef __attribute__((ext_vector_type(4))) float f32x4;

__device__ __forceinline__ unsigned pack_bf16x2(float a, float b){
  unsigned ua = __float_as_uint(a);
  unsigned ub = __float_as_uint(b);
  unsigned ra = (ua + 0x7fffu + ((ua >> 16) & 1u)) >> 16;   // RNE round to bf16
  unsigned rb = (ub + 0x7fffu + ((ub >> 16) & 1u)) >> 16;
  return ra | (rb << 16);
}
__device__ __forceinline__ float bf_lo(unsigned u){ return __uint_as_float(u << 16); }
__device__ __forceinline__ float bf_hi(unsigned u){ return __uint_as_float(u & 0xffff0000u); }

// h0 = pack_bf16(PQ @ W_in + b_in) ; V = (1,0).  h stored as bf16x2 (64 uints/node).
__global__ void init_kernel(const float* __restrict__ PQ, const float* __restrict__ Win,
                            const float* __restrict__ bin, unsigned* __restrict__ h,
                            float* __restrict__ V, int N){
  int lane = threadIdx.x & 63;
  int wid  = (blockIdx.x * blockDim.x + threadIdx.x) >> 6;
  int nw   = (gridDim.x * blockDim.x) >> 6;
  int c0 = 2*lane, c1 = c0 + 1;
  float w00 = Win[c0], w01 = Win[c1], w10 = Win[H+c0], w11 = Win[H+c1];
  float b0 = bin[c0], b1 = bin[c1];
  for (int n = wid; n < N; n += nw){
    float p0 = PQ[2*n], p1 = PQ[2*n+1];
    float h0 = p0*w00 + p1*w10 + b0;
    float h1 = p0*w01 + p1*w11 + b1;
    h[(size_t)n*64 + lane] = pack_bf16x2(h0, h1);
    if (lane == 0){ V[2*n] = 1.0f; V[2*n+1] = 0.0f; }
  }
}

__global__ void hist_kernel(const int* __restrict__ recv, int* __restrict__ deg, int E){
  int i = blockIdx.x*blockDim.x + threadIdx.x;
  int st = gridDim.x*blockDim.x;
  for (; i < E; i += st) atomicAdd(deg + recv[i], 1);
}

// ---- 3-phase device-wide exclusive scan of deg[N] ----
__global__ void scan1_kernel(const int* __restrict__ deg, int* __restrict__ rowptr,
                             int* __restrict__ bsum, int N){
  __shared__ int s[SCAN_B];
  int t = threadIdx.x;
  int i = blockIdx.x*SCAN_B + t;
  int v = (i < N) ? deg[i] : 0;
  s[t] = v; __syncthreads();
  #pragma unroll
  for (int off = 1; off < SCAN_B; off <<= 1){
    int x = (t >= off) ? s[t-off] : 0;
    __syncthreads();
    s[t] += x;
    __syncthreads();
  }
  int incl = s[t];
  if (i < N) rowptr[i] = incl - v;            // block-local exclusive
  if (t == SCAN_B-1) bsum[blockIdx.x] = incl; // block total
}

__global__ void scan2_kernel(int* __restrict__ bsum, int* __restrict__ bexcl, int nb){
  __shared__ int s[SCAN_B];
  int t = threadIdx.x;
  int v = (t < nb) ? bsum[t] : 0;
  s[t] = v; __syncthreads();
  #pragma unroll
  for (int off = 1; off < SCAN_B; off <<= 1){
    int x = (t >= off) ? s[t-off] : 0;
    __syncthreads();
    s[t] += x;
    __syncthreads();
  }
  if (t < nb) bexcl[t] = s[t] - v;
}

__global__ void scan3_kernel(int* __restrict__ rowptr, int* __restrict__ cursor,
                             const int* __restrict__ bexcl, int N, int E){
  int i = blockIdx.x*SCAN_B + threadIdx.x;
  if (i < N){
    int r = rowptr[i] + bexcl[blockIdx.x];
    rowptr[i] = r;
    cursor[i] = r;
  }
  if (i == 0) rowptr[N] = E;
}

// single 8B scatter per edge: (sender, edge-id) packed.
__global__ void fill_kernel(const int* __restrict__ recv, const int* __restrict__ send,
                            int* __restrict__ cursor, uint2* __restrict__ epk, int E){
  int i = blockIdx.x*blockDim.x + threadIdx.x;
  int st = gridDim.x*blockDim.x;
  for (; i < E; i += st){
    int pos = atomicAdd(cursor + recv[i], 1);
    epk[pos] = make_uint2((unsigned)send[i], (unsigned)i);
  }
}

// Pre-pack Wh (rows 2..129 of Wmsg, [128][128]) into per-lane MFMA B-fragment
// order, bf16x2.  Fragment f = ct*4+ks; lane holds B[k=ks*32+(lane>>4)*8+j][col=ct*16+(lane&15)].
__global__ void wprep_kernel(const float* __restrict__ Wmsg, unsigned* __restrict__ Wb, int L){
  int t = blockIdx.x*blockDim.x + threadIdx.x;
  if (t >= L*2048) return;
  int layer = t >> 11;
  int f = t & 2047;
  int ct   = f >> 8;
  int ks   = (f >> 6) & 3;
  int lane = f & 63;
  int col = ct*16 + (lane & 15);
  int kbase = ks*32 + (lane >> 4)*8;
  const float* Wl = Wmsg + (size_t)layer*134*H + 2*H;   // Wh rows
  unsigned u0 = pack_bf16x2(Wl[(size_t)(kbase+0)*H + col], Wl[(size_t)(kbase+1)*H + col]);
  unsigned u1 = pack_bf16x2(Wl[(size_t)(kbase+2)*H + col], Wl[(size_t)(kbase+3)*H + col]);
  unsigned u2 = pack_bf16x2(Wl[(size_t)(kbase+4)*H + col], Wl[(size_t)(kbase+5)*H + col]);
  unsigned u3 = pack_bf16x2(Wl[(size_t)(kbase+6)*H + col], Wl[(size_t)(kbase+7)*H + col]);
  uint4* dst = reinterpret_cast<uint4*>(Wb) + (size_t)layer*2048 + f;
  *dst = make_uint4(u0, u1, u2, u3);
}

// msrc = pack_bf16( h @ Wh  +  V @ Wv + b )  via MFMA (16 nodes/wave).
__global__ void node_msg_mfma(const float* __restrict__ V, const unsigned* __restrict__ h,
                              const float* __restrict__ Wmsg_l, const float* __restrict__ bmsg_l,
                              const unsigned* __restrict__ Wb_l, unsigned* __restrict__ msrc, int N){
  int lane = threadIdx.x & 63;
  int gw   = (blockIdx.x*blockDim.x + threadIdx.x) >> 6;
  int nwv  = (gridDim.x*blockDim.x) >> 6;
  int row = lane & 15, kg = lane >> 4;
  int ntiles = N >> 4;                      // N divisible by 16
  const bf16x8* wb = reinterpret_cast<const bf16x8*>(Wb_l);
  for (int t = gw; t < ntiles; t += nwv){
    int node0 = t << 4;
    const bf16x8* hrow = reinterpret_cast<const bf16x8*>(h + (size_t)(node0 + row)*64);
    bf16x8 a[4];
    #pragma unroll
    for (int ks = 0; ks < 4; ++ks) a[ks] = hrow[ks*4 + kg];
    float2 vv[4];
    #pragma unroll
    for (int r = 0; r < 4; ++r)
      vv[r] = *reinterpret_cast<const float2*>(V + 2*(node0 + kg*4 + r));
    #pragma unroll
    for (int ct = 0; ct < 8; ++ct){
      f32x4 acc = {0.f, 0.f, 0.f, 0.f};
      #pragma unroll
      for (int ks = 0; ks < 4; ++ks){
        bf16x8 b = wb[(ct*4 + ks)*64 + lane];
        acc = __builtin_amdgcn_mfma_f32_16x16x32_bf16(a[ks], b, acc, 0, 0, 0);
      }
      int col = ct*16 + row;
      float wv0 = Wmsg_l[col], wv1 = Wmsg_l[H + col], bb = bmsg_l[col];
      #pragma unroll
      for (int r = 0; r < 4; ++r){
        float o = acc[r] + vv[r].x*wv0 + vv[r].y*wv1 + bb;
        float oh = __shfl_xor(o, 1, 64);
        if (!(lane & 1)){
          int nr = node0 + kg*4 + r;
          msrc[(size_t)nr*64 + ct*8 + (row >> 1)] = pack_bf16x2(o, oh);
        }
      }
    }
  }
}

// per receiver node: acc = sum_e m_src[s_e] (+ ef term); h=relu(acc) bf16;
// dV = h@W_out + b_out; V += dV.  One wave/node, 2 edges processed per VMEM
// wave-issue: half-wave 0 = edge j, half-wave 1 = edge j+1; lane holds 4 cols
// (uint2 of msrc).  Pair-unroll x4 -> 8 edges in flight.
template<bool FIRST>
__global__ void agg_update_kernel(const unsigned* __restrict__ msrc,
                                  const int* __restrict__ rowptr,
                                  const uint2* __restrict__ epk,
                                  const float* __restrict__ ef,
                                  const float* __restrict__ Wmsg_l,
                                  const float* __restrict__ Wout_l,
                                  const float* __restrict__ bout_l,
                                  const float* __restrict__ Vin,
                                  float* __restrict__ Vout,
                                  unsigned* __restrict__ h,
                                  float4* __restrict__ efsum, int N){
  int lane = threadIdx.x & 63;
  int wid  = (blockIdx.x*blockDim.x + threadIdx.x) >> 6;
  int nw   = (gridDim.x*blockDim.x) >> 6;
  int half = lane >> 5;
  int m    = lane & 31;           // lane owns cols 4m..4m+3
  float We[4][4], Wo0[4], Wo1[4];
  #pragma unroll
  for (int k = 0; k < 4; ++k){
    int col = 4*m + k;
    #pragma unroll
    for (int r = 0; r < 4; ++r) We[r][k] = Wmsg_l[(size_t)(130+r)*H + col];
    Wo0[k] = Wout_l[col*2]; Wo1[k] = Wout_l[col*2+1];
  }
  float bo0 = bout_l[0], bo1 = bout_l[1];
  for (int n = wid; n < N; n += nw){
    int beg = rowptr[n], end = rowptr[n+1];
    float a0 = 0.f, a1 = 0.f, a2 = 0.f, a3 = 0.f;
    float sfx = 0.f, sfy = 0.f, sfz = 0.f, sfw = 0.f;
    for (int c = beg; c < end; c += 64){
      int idx = c + lane;
      bool inl = idx < end;
      uint2 ep = inl ? epk[idx] : make_uint2(0u, 0u);
      int sv = (int)ep.x;
      if (FIRST && inl){
        float4 f = *reinterpret_cast<const float4*>(ef + (size_t)ep.y*4);
        sfx += f.x; sfy += f.y; sfz += f.z; sfw += f.w;
      }
      int kmax = min(64, end - c);
      int j = 0;
      for (; j + 8 <= kmax; j += 8){
        int s0 = __shfl(sv, j+0+half, 64);
        int s1 = __shfl(sv, j+2+half, 64);
        int s2 = __shfl(sv, j+4+half, 64);
        int s3 = __shfl(sv, j+6+half, 64);
        uint2 u0 = *reinterpret_cast<const uint2*>(msrc + (size_t)s0*64 + 2*m);
        uint2 u1 = *reinterpret_cast<const uint2*>(msrc + (size_t)s1*64 + 2*m);
        uint2 u2 = *reinterpret_cast<const uint2*>(msrc + (size_t)s2*64 + 2*m);
        uint2 u3 = *reinterpret_cast<const uint2*>(msrc + (size_t)s3*64 + 2*m);
        a0 += bf_lo(u0.x) + bf_lo(u1.x) + bf_lo(u2.x) + bf_lo(u3.x);
        a1 += bf_hi(u0.x) + bf_hi(u1.x) + bf_hi(u2.x) + bf_hi(u3.x);
        a2 += bf_lo(u0.y) + bf_lo(u1.y) + bf_lo(u2.y) + bf_lo(u3.y);
        a3 += bf_hi(u0.y) + bf_hi(u1.y) + bf_hi(u2.y) + bf_hi(u3.y);
      }
      for (; j < kmax; j += 2){
        int jj = j + half;
        bool v = jj < kmax;
        int s = __shfl(sv, v ? jj : 0, 64);
        uint2 u = *reinterpret_cast<const uint2*>(msrc + (size_t)s*64 + 2*m);
        if (v){
          a0 += bf_lo(u.x); a1 += bf_hi(u.x);
          a2 += bf_lo(u.y); a3 += bf_hi(u.y);
        }
      }
    }
    // combine the two half-wave edge partitions
    a0 += __shfl_xor(a0, 32, 64);
    a1 += __shfl_xor(a1, 32, 64);
    a2 += __shfl_xor(a2, 32, 64);
    a3 += __shfl_xor(a3, 32, 64);
    if (FIRST){
      #pragma unroll
      for (int off = 32; off > 0; off >>= 1){
        sfx += __shfl_xor(sfx, off, 64);
        sfy += __shfl_xor(sfy, off, 64);
        sfz += __shfl_xor(sfz, off, 64);
        sfw += __shfl_xor(sfw, off, 64);
      }
      if (lane == 0) efsum[n] = make_float4(sfx, sfy, sfz, sfw);
    } else {
      float4 f = efsum[n];
      sfx = f.x; sfy = f.y; sfz = f.z; sfw = f.w;
    }
    a0 += sfx*We[0][0] + sfy*We[1][0] + sfz*We[2][0] + sfw*We[3][0];
    a1 += sfx*We[0][1] + sfy*We[1][1] + sfz*We[2][1] + sfw*We[3][1];
    a2 += sfx*We[0][2] + sfy*We[1][2] + sfz*We[2][2] + sfw*We[3][2];
    a3 += sfx*We[0][3] + sfy*We[1][3] + sfz*We[2][3] + sfw*We[3][3];
    a0 = fmaxf(a0, 0.f); a1 = fmaxf(a1, 0.f);
    a2 = fmaxf(a2, 0.f); a3 = fmaxf(a3, 0.f);
    if (half == 0){
      uint2 hv = make_uint2(pack_bf16x2(a0, a1), pack_bf16x2(a2, a3));
      *reinterpret_cast<uint2*>(h + (size_t)n*64 + 2*m) = hv;
    }
    float p0 = a0*Wo0[0] + a1*Wo0[1] + a2*Wo0[2] + a3*Wo0[3];
    float p1 = a0*Wo1[0] + a1*Wo1[1] + a2*Wo1[2] + a3*Wo1[3];
    #pragma unroll
    for (int off = 16; off > 0; off >>= 1){
      p0 += __shfl_xor(p0, off, 64);
      p1 += __shfl_xor(p1, off, 64);
    }
    if (lane == 0){
      float v0 = Vin[2*n], v1 = Vin[2*n+1];
      Vout[2*n]   = v0 + p0 + bo0;
      Vout[2*n+1] = v1 + p1 + bo1;
    }
  }
}

extern "C" void kernel_launch(void* const* d_in, const int* in_sizes, int n_in,
                              void* d_out, int out_size, void* d_ws, size_t ws_size,
                              hipStream_t stream){
  const float* PQ      = (const float*)d_in[0];
  const int*   senders = (const int*)  d_in[1];
  const int*   recv    = (const int*)  d_in[2];
  const float* ef      = (const float*)d_in[3];
  const float* Win     = (const float*)d_in[4];
  const float* bin     = (const float*)d_in[5];
  const float* Wmsg    = (const float*)d_in[6];
  const float* bmsg    = (const float*)d_in[7];
  const float* Wout    = (const float*)d_in[8];
  const float* bout    = (const float*)d_in[9];
  int N = in_sizes[0] / 2;
  int E = in_sizes[1];
  int L = in_sizes[7] / H;          // 3 layers

  char* base = (char*)d_ws;
  size_t off = 0;
  auto alloc = [&](size_t bytes)->char*{
    char* p = base + off; off += (bytes + 255) & ~(size_t)255; return p;
  };
  unsigned* h      = (unsigned*)alloc((size_t)N*64*4);   // bf16x2-packed
  unsigned* msrc   = (unsigned*)alloc((size_t)N*64*4);
  float*    V      = (float*)   alloc((size_t)N*2*4);
  int*      deg    = (int*)     alloc((size_t)N*4);
  int*      rowptr = (int*)     alloc((size_t)(N+1)*4);
  int*      cursor = (int*)     alloc((size_t)N*4);
  uint2*    epk    = (uint2*)   alloc((size_t)E*8);
  float4*   efsum  = (float4*)  alloc((size_t)N*16);
  int*      bsum   = (int*)     alloc((size_t)SCAN_B*4);
  int*      bexcl  = (int*)     alloc((size_t)SCAN_B*4);
  unsigned* Wb     = (unsigned*)alloc((size_t)L*2048*16); // MFMA B fragments
  if (off > ws_size) return;

  int nb = (N + SCAN_B - 1) / SCAN_B;   // 98 blocks

  hipMemsetAsync(deg, 0, (size_t)N*4, stream);
  init_kernel<<<2048, 256, 0, stream>>>(PQ, Win, bin, h, V, N);
  hist_kernel<<<1024, 256, 0, stream>>>(recv, deg, E);
  scan1_kernel<<<nb, SCAN_B, 0, stream>>>(deg, rowptr, bsum, N);
  scan2_kernel<<<1, SCAN_B, 0, stream>>>(bsum, bexcl, nb);
  scan3_kernel<<<nb, SCAN_B, 0, stream>>>(rowptr, cursor, bexcl, N, E);
  fill_kernel<<<1024, 256, 0, stream>>>(recv, senders, cursor, epk, E);
  wprep_kernel<<<(L*2048 + 255)/256, 256, 0, stream>>>(Wmsg, Wb, L);

  for (int l = 0; l < L; ++l){
    const float* Wmsg_l = Wmsg + (size_t)l*134*H;
    const float* bmsg_l = bmsg + (size_t)l*H;
    const float* Wout_l = Wout + (size_t)l*H*2;
    const float* bout_l = bout + (size_t)l*2;
    const unsigned* Wb_l = Wb + (size_t)l*2048*4;
    node_msg_mfma<<<1568, 256, 0, stream>>>(V, h, Wmsg_l, bmsg_l, Wb_l, msrc, N);
    float* Vout = (l == L-1) ? (float*)d_out : V;
    if (l == 0)
      agg_update_kernel<true><<<2048, 256, 0, stream>>>(msrc, rowptr, epk, ef,
                                                        Wmsg_l, Wout_l, bout_l, V, Vout, h, efsum, N);
    else
      agg_update_kernel<false><<<2048, 256, 0, stream>>>(msrc, rowptr, epk, ef,
                                                         Wmsg_l, Wout_l, bout_l, V, Vout, h, efsum, N);
  }
}